// Round 16
// baseline (1829.989 us; speedup 1.0000x reference)
//
#include <hip/hip_runtime.h>
#include <hip/hip_bf16.h>

#define DD 64
#define C_REL 40
#define C_SIM 80
#define SLICE 512

static inline int cdiv(long long a, long long b) { return (int)((a + b - 1) / b); }

// ================= sim graphs: LDS-partitioned atomic-free CSR build =================
// Workgroup w < nsU owns UU destination slice [w*SLICE, ...); else II slice.
// Sweeps the whole edge list (coalesced), LDS atomics only, sequential global writes.
__global__ __launch_bounds__(256) void k_build_sim(const int* __restrict__ eiU, const int* __restrict__ eiI,
                                                   int E, int U, int I, int nsU,
                                                   int* __restrict__ cnt, float* __restrict__ dinv,
                                                   unsigned short* __restrict__ edpU,
                                                   unsigned short* __restrict__ edpI) {
    extern __shared__ char smem[];
    int* cnt_s = (int*)smem;                                      // SLICE ints
    unsigned short* slots_s = (unsigned short*)(smem + SLICE * 4); // SLICE*C_SIM ushorts
    int tid = threadIdx.x;
    bool isU = (int)blockIdx.x < nsU;
    int sl = isU ? blockIdx.x : blockIdx.x - nsU;
    int n = isU ? U : I;
    int lo = sl * SLICE;
    int len = n - lo; if (len > SLICE) len = SLICE;
    if (len <= 0) return;
    const int* row = isU ? eiU : eiI;
    const int* col = row + E;

    for (int i = tid; i < len; i += 256) cnt_s[i] = 0;
    __syncthreads();

    if (((E & 3) == 0) && ((((size_t)col) & 15) == 0)) {
        for (int e = tid * 4; e + 3 < E; e += 1024) {
            int4 c4 = *(const int4*)(col + e);
            unsigned l0 = (unsigned)(c4.x - lo), l1 = (unsigned)(c4.y - lo);
            unsigned l2 = (unsigned)(c4.z - lo), l3 = (unsigned)(c4.w - lo);
            if (l0 < (unsigned)len) { int pos = atomicAdd(&cnt_s[l0], 1); if (pos < C_SIM) slots_s[l0 * C_SIM + pos] = (unsigned short)row[e]; }
            if (l1 < (unsigned)len) { int pos = atomicAdd(&cnt_s[l1], 1); if (pos < C_SIM) slots_s[l1 * C_SIM + pos] = (unsigned short)row[e + 1]; }
            if (l2 < (unsigned)len) { int pos = atomicAdd(&cnt_s[l2], 1); if (pos < C_SIM) slots_s[l2 * C_SIM + pos] = (unsigned short)row[e + 2]; }
            if (l3 < (unsigned)len) { int pos = atomicAdd(&cnt_s[l3], 1); if (pos < C_SIM) slots_s[l3 * C_SIM + pos] = (unsigned short)row[e + 3]; }
        }
    } else {
        for (int e = tid; e < E; e += 256) {
            unsigned l = (unsigned)(col[e] - lo);
            if (l < (unsigned)len) { int pos = atomicAdd(&cnt_s[l], 1); if (pos < C_SIM) slots_s[l * C_SIM + pos] = (unsigned short)row[e]; }
        }
    }
    __syncthreads();

    int goff = (isU ? 0 : U) + lo;
    for (int i = tid; i < len; i += 256) {
        int d = cnt_s[i];
        cnt[goff + i] = d;
        dinv[goff + i] = d > 0 ? rsqrtf((float)d) : 0.f;
    }
    // slots: len*C_SIM ushorts = len*160 B (16B-divisible), sequential uint4 copy
    unsigned short* dst = (isU ? edpU : edpI) + (size_t)lo * C_SIM;
    int n16 = len * C_SIM / 8;   // uint4 = 8 ushorts
    const uint4* s4 = (const uint4*)slots_s;
    uint4* d4 = (uint4*)dst;
    for (int i = tid; i < n16; i += 256) d4[i] = s4[i];
}

// ================= gathers (ushort slots) =================

// full-node gather (sim layer 1): 16 threads/node, float4 slice each.
__global__ __launch_bounds__(256) void k_gather_pad(const float* __restrict__ src, float* __restrict__ dst,
                                                    const unsigned short* __restrict__ edp,
                                                    const int* __restrict__ cnt,
                                                    const float* __restrict__ dinv, int nNodes) {
    int t = blockIdx.x * blockDim.x + threadIdx.x;
    int node = t >> 4;
    if (node >= nNodes) return;
    int k4 = (t & 15) << 2;
    int deg = cnt[node]; if (deg > C_SIM) deg = C_SIM;
    float dc = dinv[node];
    const unsigned short* lst = edp + (size_t)node * C_SIM;
    float4 acc = make_float4(0.f, 0.f, 0.f, 0.f);
    for (int e = 0; e < deg; ++e) {
        int rs = lst[e];
        float nn = dc * dinv[rs];
        float4 v = *(const float4*)(src + (size_t)rs * DD + k4);
        acc.x += nn * v.x; acc.y += nn * v.y; acc.z += nn * v.z; acc.w += nn * v.w;
    }
    *(float4*)(dst + (size_t)node * DD + k4) = acc;
}

// selected-node gather (sim layer 2): dst row j = propagate(src)[idx[j]]
__global__ __launch_bounds__(256) void k_gather_sel_sim(const float* __restrict__ src, float* __restrict__ dst,
                                                        const unsigned short* __restrict__ edp,
                                                        const int* __restrict__ cnt,
                                                        const float* __restrict__ dinv,
                                                        const int* __restrict__ idx, int B) {
    int t = blockIdx.x * blockDim.x + threadIdx.x;
    int j = t >> 4;
    if (j >= B) return;
    int k4 = (t & 15) << 2;
    int node = idx[j];
    int deg = cnt[node]; if (deg > C_SIM) deg = C_SIM;
    float dc = dinv[node];
    const unsigned short* lst = edp + (size_t)node * C_SIM;
    float4 acc = make_float4(0.f, 0.f, 0.f, 0.f);
    for (int e = 0; e < deg; ++e) {
        int rs = lst[e];
        float nn = dc * dinv[rs];
        float4 v = *(const float4*)(src + (size_t)rs * DD + k4);
        acc.x += nn * v.x; acc.y += nn * v.y; acc.z += nn * v.z; acc.w += nn * v.w;
    }
    *(float4*)(dst + (size_t)j * DD + k4) = acc;
}

// ================= relational pass (R12 structure, measured) =================

// mark selected destination nodes
__global__ void k_mark(unsigned char* __restrict__ sel, const int* __restrict__ user,
                       const int* __restrict__ item, int B, int U) {
    int t = blockIdx.x * blockDim.x + threadIdx.x;
    if (t >= 2 * B) return;
    int node = (t < B) ? user[t] : (U + item[t - B]);
    sel[node] = 1;
}

// rel scatter: full histogram (all dinv needed), slot write ONLY for selected destinations
__global__ void k_scatter_rel(const int* __restrict__ row, const int* __restrict__ col, int E,
                              int* __restrict__ cnt, int* __restrict__ edp,
                              const unsigned char* __restrict__ sel) {
    int e = blockIdx.x * blockDim.x + threadIdx.x;
    if (e >= E) return;
    int r = row[e], c = col[e];
    int pos = atomicAdd(&cnt[c], 1);
    if (sel[c] && pos < C_REL) edp[(size_t)c * C_REL + pos] = r;
}

// rel gather of RAW x0 rows (prop commutes with W): TMP[j] = sum_e nn * x0[rs]
__global__ __launch_bounds__(256) void k_gather_x0_rel(const float* __restrict__ Gu, const float* __restrict__ Gi,
                                                       int U, float* __restrict__ TMP,
                                                       const int* __restrict__ edp, const int* __restrict__ cnt,
                                                       const int* __restrict__ user,
                                                       const int* __restrict__ item, int B) {
    int t = blockIdx.x * blockDim.x + threadIdx.x;
    int j = t >> 4;
    if (j >= 2 * B) return;
    int k4 = (t & 15) << 2;
    int node = (j < B) ? user[j] : (U + item[j - B]);
    int cn = cnt[node];
    int deg = cn > C_REL ? C_REL : cn;
    float dc = cn > 0 ? rsqrtf((float)cn) : 0.f;
    const int* lst = edp + (size_t)node * C_REL;
    float4 acc = make_float4(0.f, 0.f, 0.f, 0.f);
    for (int e = 0; e < deg; ++e) {
        int rs = lst[e];
        int cr = cnt[rs];
        float nn = dc * (cr > 0 ? rsqrtf((float)cr) : 0.f);
        const float* srow = (rs < U) ? (Gu + (size_t)rs * DD) : (Gi + (size_t)(rs - U) * DD);
        float4 v = *(const float4*)(srow + k4);
        acc.x += nn * v.x; acc.y += nn * v.y; acc.z += nn * v.z; acc.w += nn * v.w;
    }
    *(float4*)(TMP + (size_t)j * DD + k4) = acc;
}

// ================= dense pieces =================

template <bool RELU_ACC>
__global__ __launch_bounds__(256) void k_matmul64t(const float* __restrict__ X, const float* __restrict__ W,
                                                   float* __restrict__ out, int Nrows) {
    __shared__ float Wl[64 * 64];
    int tid = threadIdx.x;
    for (int t = tid; t < 1024; t += 256) ((float4*)Wl)[t] = ((const float4*)W)[t];
    __syncthreads();
    int row = blockIdx.x * 64 + (tid >> 2);
    if (row >= Nrows) return;
    const float* xs = X + (size_t)row * DD;
    int j0 = (tid & 3) << 4;
    float acc[16];
#pragma unroll
    for (int j = 0; j < 16; ++j) acc[j] = 0.f;
#pragma unroll 4
    for (int k = 0; k < 64; k += 4) {
        float4 xv = *(const float4*)(xs + k);
        const float* w0 = Wl + k * 64 + j0;
#pragma unroll
        for (int j = 0; j < 16; ++j) acc[j] += xv.x * w0[j];
#pragma unroll
        for (int j = 0; j < 16; ++j) acc[j] += xv.y * w0[64 + j];
#pragma unroll
        for (int j = 0; j < 16; ++j) acc[j] += xv.z * w0[128 + j];
#pragma unroll
        for (int j = 0; j < 16; ++j) acc[j] += xv.w * w0[192 + j];
    }
    float* o = out + (size_t)row * DD + j0;
    if (RELU_ACC) {
#pragma unroll
        for (int j = 0; j < 4; ++j) {
            float4 cur = ((float4*)o)[j];
            cur.x += fmaxf(acc[4 * j + 0], 0.f);
            cur.y += fmaxf(acc[4 * j + 1], 0.f);
            cur.z += fmaxf(acc[4 * j + 2], 0.f);
            cur.w += fmaxf(acc[4 * j + 3], 0.f);
            ((float4*)o)[j] = cur;
        }
    } else {
#pragma unroll
        for (int j = 0; j < 4; ++j)
            ((float4*)o)[j] = make_float4(acc[4 * j], acc[4 * j + 1], acc[4 * j + 2], acc[4 * j + 3]);
    }
}

// gu[j] = 0.5*(gus_sel[j] + EMB[j]) for j<B; gi likewise
__global__ void k_blend(const float* __restrict__ gus_sel, const float* __restrict__ gis_sel,
                        const float* __restrict__ EMB, float* __restrict__ gu, float* __restrict__ gi,
                        int B) {
    int t = blockIdx.x * blockDim.x + threadIdx.x;
    if (t >= 2 * B * 16) return;
    int j = t >> 4, k = t & 15;
    float4 e = ((const float4*)(EMB + (size_t)j * DD))[k];
    if (j < B) {
        float4 s = ((const float4*)(gus_sel + (size_t)j * DD))[k];
        ((float4*)(gu + (size_t)j * DD))[k] =
            make_float4(0.5f * (s.x + e.x), 0.5f * (s.y + e.y), 0.5f * (s.z + e.z), 0.5f * (s.w + e.w));
    } else {
        int jj = j - B;
        float4 s = ((const float4*)(gis_sel + (size_t)jj * DD))[k];
        ((float4*)(gi + (size_t)jj * DD))[k] =
            make_float4(0.5f * (s.x + e.x), 0.5f * (s.y + e.y), 0.5f * (s.z + e.z), 0.5f * (s.w + e.w));
    }
}

// Q[r,d,e] = sum_s A[r,s]*P[s,d,e]
__global__ void k_build_Q(const float* __restrict__ A, const float* __restrict__ P,
                          float* __restrict__ Q, int R, int S) {
    int t = blockIdx.x * blockDim.x + threadIdx.x;
    if (t >= R * 4096) return;
    int r = t / 4096, de = t % 4096;
    float acc = 0.f;
    for (int s = 0; s < S; ++s) acc += A[r * S + s] * P[(size_t)s * 4096 + de];
    Q[t] = acc;
}

// pui[b,r]: one 64-lane wave per (b,r)
__global__ __launch_bounds__(256) void k_pui2(const float* __restrict__ gu, const float* __restrict__ gi,
                                              const float* __restrict__ Q, float* __restrict__ pout,
                                              int B, int R) {
    int wid = (int)(((long long)blockIdx.x * blockDim.x + threadIdx.x) >> 6);
    int lane = threadIdx.x & 63;
    if (wid >= B * R) return;
    int b = wid / R, r = wid % R;
    const float* Qr = Q + (size_t)r * 4096;
    float gu_l = gu[(size_t)b * DD + lane];
    float gi_l = gi[(size_t)b * DD + lane];
    float acc = 0.f;
#pragma unroll 8
    for (int d = 0; d < 64; ++d) {
        float gud = __shfl(gu_l, d, 64);
        acc += gud * Qr[d * 64 + lane];
    }
    acc *= gi_l;
#pragma unroll
    for (int off = 32; off > 0; off >>= 1) acc += __shfl_down(acc, off, 64);
    if (lane == 0) pout[wid] = acc;
}

// xui[b] = sum_r rel[r]*softmax(pui[b,:])[r]
__global__ void k_softmax_out(const float* __restrict__ pui, const float* __restrict__ rel,
                              float* __restrict__ xui, int B, int R) {
    int b = blockIdx.x * blockDim.x + threadIdx.x;
    if (b >= B) return;
    float m = -1e30f;
    for (int r = 0; r < R; ++r) m = fmaxf(m, pui[(size_t)b * R + r]);
    float se = 0.f, sw = 0.f;
    for (int r = 0; r < R; ++r) {
        float e = expf(pui[(size_t)b * R + r] - m);
        se += e; sw += rel[r] * e;
    }
    xui[b] = sw / se;
}

extern "C" void kernel_launch(void* const* d_in, const int* in_sizes, int n_in,
                              void* d_out, int out_size, void* d_ws, size_t ws_size,
                              hipStream_t stream) {
    const float* Gu      = (const float*)d_in[0];
    const float* Gi      = (const float*)d_in[1];
    const float* Gus     = (const float*)d_in[2];
    const float* Gis     = (const float*)d_in[3];
    const float* W_conv  = (const float*)d_in[4];
    const float* W_dense = (const float*)d_in[5];
    const float* P       = (const float*)d_in[6];
    const float* A       = (const float*)d_in[7];
    const float* rel     = (const float*)d_in[8];
    const int*   ei_rel  = (const int*)d_in[9];
    const int*   ei_uu   = (const int*)d_in[10];
    const int*   ei_ii   = (const int*)d_in[11];
    const int*   user    = (const int*)d_in[12];
    const int*   item    = (const int*)d_in[13];

    const int U = in_sizes[0] / DD;
    const int I = in_sizes[1] / DD;
    const int N = U + I;
    const int R = in_sizes[8];
    const int S = in_sizes[6] / 4096;
    const int E_REL = in_sizes[9] / (2 * R);
    const int E_SIM = in_sizes[10] / 2;
    const int B = in_sizes[12];
    const size_t RN = (size_t)R * N;
    const int maxUI = U > I ? U : I;

    // ---- workspace layout (16B-aligned) ----
    char* p = (char*)d_ws;
    unsigned short* edpU = (unsigned short*)p; p += (((size_t)U * C_SIM * 2 + 15) & ~(size_t)15);
    unsigned short* edpI = (unsigned short*)p; p += (((size_t)I * C_SIM * 2 + 15) & ~(size_t)15);
    int*   edpR    = (int*)p;   p += (size_t)N * C_REL * 4;
    int*   cntSim  = (int*)p;   p += (size_t)N * 4;
    int*   cntRel  = (int*)p;   p += RN * 4;
    float* dinv    = (float*)p; p += (size_t)N * 4;
    unsigned char* sel = (unsigned char*)p; p += ((size_t)N + 15) & ~(size_t)15;
    float* gus_sel = (float*)p; p += (size_t)B * DD * 4;
    float* gis_sel = (float*)p; p += (size_t)B * DD * 4;
    float* ACC     = (float*)p; p += (size_t)2 * B * DD * 4;
    float* TMP     = (float*)p; p += (size_t)2 * B * DD * 4;
    float* EMB     = (float*)p; p += (size_t)2 * B * DD * 4;
    float* gu      = (float*)p; p += (size_t)B * DD * 4;
    float* gi      = (float*)p; p += (size_t)B * DD * 4;
    float* Q       = (float*)p; p += (size_t)R * 4096 * 4;
    float* BIG0    = (float*)p; p += (size_t)maxUI * DD * 4;  // sim layer-1 out

    float* xui = (float*)d_out;
    float* pui = (float*)d_out + B;

    const int BT = 256;

    // ======== similarity graphs: atomic-free LDS-partitioned CSR build ========
    {
        int nsU = cdiv(U, SLICE), nsI = cdiv(I, SLICE);
        size_t lds = (size_t)SLICE * 4 + (size_t)SLICE * C_SIM * 2;  // 84 KB
        k_build_sim<<<nsU + nsI, BT, lds, stream>>>(ei_uu, ei_ii, E_SIM, U, I, nsU,
                                                    cntSim, dinv, edpU, edpI);
    }
    // UU gathers
    k_gather_pad<<<cdiv((long long)U * 16, BT), BT, 0, stream>>>(Gus, BIG0, edpU, cntSim, dinv, U);
    k_gather_sel_sim<<<cdiv((long long)B * 16, BT), BT, 0, stream>>>(BIG0, gus_sel, edpU, cntSim, dinv, user, B);
    // II gathers
    k_gather_pad<<<cdiv((long long)I * 16, BT), BT, 0, stream>>>(Gis, BIG0, edpI, cntSim + U, dinv + U, I);
    k_gather_sel_sim<<<cdiv((long long)B * 16, BT), BT, 0, stream>>>(BIG0, gis_sel, edpI, cntSim + U, dinv + U, item, B);

    // ======== relational pass (R12 structure) ========
    hipMemsetAsync(cntRel, 0, RN * 4, stream);
    hipMemsetAsync(sel, 0, (size_t)N, stream);
    hipMemsetAsync(ACC, 0, (size_t)2 * B * DD * 4, stream);
    k_mark<<<cdiv(2 * B, BT), BT, 0, stream>>>(sel, user, item, B, U);
    for (int r = 0; r < R; ++r) {
        const int* rrow = ei_rel + (size_t)r * 2 * E_REL;
        const int* rcol = rrow + E_REL;
        k_scatter_rel<<<cdiv(E_REL, BT), BT, 0, stream>>>(rrow, rcol, E_REL, cntRel + (size_t)r * N, edpR, sel);
        k_gather_x0_rel<<<cdiv((long long)2 * B * 16, BT), BT, 0, stream>>>(Gu, Gi, U, TMP, edpR,
                                                                            cntRel + (size_t)r * N, user, item, B);
        k_matmul64t<true><<<cdiv(2 * B, 64), BT, 0, stream>>>(TMP, W_conv + (size_t)r * 4096, ACC, 2 * B);
    }

    // ---- emb = ACC @ W_dense (2B rows); blend with sim results ----
    k_matmul64t<false><<<cdiv(2 * B, 64), BT, 0, stream>>>(ACC, W_dense, EMB, 2 * B);
    k_blend<<<cdiv((long long)2 * B * 16, BT), BT, 0, stream>>>(gus_sel, gis_sel, EMB, gu, gi, B);

    // ---- head ----
    k_build_Q<<<cdiv((long long)R * 4096, BT), BT, 0, stream>>>(A, P, Q, R, S);
    k_pui2<<<cdiv((long long)B * R * 64, BT), BT, 0, stream>>>(gu, gi, Q, pui, B, R);
    k_softmax_out<<<cdiv(B, BT), BT, 0, stream>>>(pui, rel, xui, B, R);
}

// Round 17
// 966.732 us; speedup vs baseline: 1.8930x; 1.8930x over previous
//
#include <hip/hip_runtime.h>
#include <hip/hip_bf16.h>

#define DD 64
#define C_REL 40
#define C_SIM 80

static inline int cdiv(long long a, long long b) { return (int)((a + b - 1) / b); }

// ================= padded-slot CSR =================

// sim scatter: full slot lists (layer-1 gather needs every node)
__global__ void k_scatter_pad(const int* __restrict__ row, const int* __restrict__ col, int E,
                              int* __restrict__ cnt, int* __restrict__ edp, int C) {
    int e = blockIdx.x * blockDim.x + threadIdx.x;
    if (e >= E) return;
    int r = row[e], c = col[e];
    int pos = atomicAdd(&cnt[c], 1);
    if (pos < C) edp[(size_t)c * C + pos] = r;
}

// rel scatter: sel-FIRST branch. Selected c (16%): returning atomic + slot write.
// Non-selected (84%): no-return atomic (count only, wave does not wait on result).
__global__ void k_scatter_rel(const int* __restrict__ row, const int* __restrict__ col, int E,
                              int* __restrict__ cnt, int* __restrict__ edp, int C,
                              const unsigned char* __restrict__ sel) {
    int e = blockIdx.x * blockDim.x + threadIdx.x;
    if (e >= E) return;
    int c = col[e];
    if (sel[c]) {
        int pos = atomicAdd(&cnt[c], 1);
        if (pos < C) edp[(size_t)c * C + pos] = row[e];
    } else {
        atomicAdd(&cnt[c], 1);   // result unused -> no-return global_atomic_add
    }
}

// mark selected destination nodes (races write same value; benign)
__global__ void k_mark(unsigned char* __restrict__ sel, const int* __restrict__ user,
                       const int* __restrict__ item, int B, int U) {
    int t = blockIdx.x * blockDim.x + threadIdx.x;
    if (t >= 2 * B) return;
    int node = (t < B) ? user[t] : (U + item[t - B]);
    sel[node] = 1;
}

// dinv[i] = deg>0 ? rsqrt(deg) : 0   (sim graphs only)
__global__ void k_dinv_i(const int* __restrict__ cnt, float* __restrict__ dinv, int n) {
    int i = blockIdx.x * blockDim.x + threadIdx.x;
    if (i < n) { int d = cnt[i]; dinv[i] = d > 0 ? rsqrtf((float)d) : 0.f; }
}

// ================= gathers =================

// full-node gather (sim layer 1): 16 threads/node, float4 slice each.
__global__ __launch_bounds__(256) void k_gather_pad(const float* __restrict__ src, float* __restrict__ dst,
                                                    const int* __restrict__ edp, const int* __restrict__ cnt,
                                                    const float* __restrict__ dinv, int C, int nNodes) {
    int t = blockIdx.x * blockDim.x + threadIdx.x;
    int node = t >> 4;
    if (node >= nNodes) return;
    int k4 = (t & 15) << 2;
    int deg = cnt[node]; if (deg > C) deg = C;
    float dc = dinv[node];
    const int* lst = edp + (size_t)node * C;
    float4 acc = make_float4(0.f, 0.f, 0.f, 0.f);
    for (int e = 0; e < deg; ++e) {
        int rs = lst[e];
        float nn = dc * dinv[rs];
        float4 v = *(const float4*)(src + (size_t)rs * DD + k4);
        acc.x += nn * v.x; acc.y += nn * v.y; acc.z += nn * v.z; acc.w += nn * v.w;
    }
    *(float4*)(dst + (size_t)node * DD + k4) = acc;
}

// selected-node gather (sim layer 2): dst row j = propagate(src)[idx[j]]
__global__ __launch_bounds__(256) void k_gather_sel_sim(const float* __restrict__ src, float* __restrict__ dst,
                                                        const int* __restrict__ edp, const int* __restrict__ cnt,
                                                        const float* __restrict__ dinv, int C,
                                                        const int* __restrict__ idx, int B) {
    int t = blockIdx.x * blockDim.x + threadIdx.x;
    int j = t >> 4;
    if (j >= B) return;
    int k4 = (t & 15) << 2;
    int node = idx[j];
    int deg = cnt[node]; if (deg > C) deg = C;
    float dc = dinv[node];
    const int* lst = edp + (size_t)node * C;
    float4 acc = make_float4(0.f, 0.f, 0.f, 0.f);
    for (int e = 0; e < deg; ++e) {
        int rs = lst[e];
        float nn = dc * dinv[rs];
        float4 v = *(const float4*)(src + (size_t)rs * DD + k4);
        acc.x += nn * v.x; acc.y += nn * v.y; acc.z += nn * v.z; acc.w += nn * v.w;
    }
    *(float4*)(dst + (size_t)j * DD + k4) = acc;
}

// rel gather of RAW x0 rows (prop commutes with W): TMP[j] = sum_e nn * x0[rs]
// norms inline from cnt (full histogram); x0 row = rs<U ? Gu[rs] : Gi[rs-U]
__global__ __launch_bounds__(256) void k_gather_x0_rel(const float* __restrict__ Gu, const float* __restrict__ Gi,
                                                       int U, float* __restrict__ TMP,
                                                       const int* __restrict__ edp, const int* __restrict__ cnt,
                                                       int C, const int* __restrict__ user,
                                                       const int* __restrict__ item, int B) {
    int t = blockIdx.x * blockDim.x + threadIdx.x;
    int j = t >> 4;
    if (j >= 2 * B) return;
    int k4 = (t & 15) << 2;
    int node = (j < B) ? user[j] : (U + item[j - B]);
    int cn = cnt[node];
    int deg = cn > C ? C : cn;
    float dc = cn > 0 ? rsqrtf((float)cn) : 0.f;
    const int* lst = edp + (size_t)node * C;
    float4 acc = make_float4(0.f, 0.f, 0.f, 0.f);
    for (int e = 0; e < deg; ++e) {
        int rs = lst[e];
        int cr = cnt[rs];
        float nn = dc * (cr > 0 ? rsqrtf((float)cr) : 0.f);
        const float* srow = (rs < U) ? (Gu + (size_t)rs * DD) : (Gi + (size_t)(rs - U) * DD);
        float4 v = *(const float4*)(srow + k4);
        acc.x += nn * v.x; acc.y += nn * v.y; acc.z += nn * v.z; acc.w += nn * v.w;
    }
    *(float4*)(TMP + (size_t)j * DD + k4) = acc;
}

// ================= dense pieces =================

// RELU_ACC ? out[i,:] += relu(X[i,:]@W) : out[i,:] = X[i,:]@W   (64x64 W)
template <bool RELU_ACC>
__global__ __launch_bounds__(256) void k_matmul64t(const float* __restrict__ X, const float* __restrict__ W,
                                                   float* __restrict__ out, int Nrows) {
    __shared__ float Wl[64 * 64];
    int tid = threadIdx.x;
    for (int t = tid; t < 1024; t += 256) ((float4*)Wl)[t] = ((const float4*)W)[t];
    __syncthreads();
    int row = blockIdx.x * 64 + (tid >> 2);
    if (row >= Nrows) return;
    const float* xs = X + (size_t)row * DD;
    int j0 = (tid & 3) << 4;
    float acc[16];
#pragma unroll
    for (int j = 0; j < 16; ++j) acc[j] = 0.f;
#pragma unroll 4
    for (int k = 0; k < 64; k += 4) {
        float4 xv = *(const float4*)(xs + k);
        const float* w0 = Wl + k * 64 + j0;
#pragma unroll
        for (int j = 0; j < 16; ++j) acc[j] += xv.x * w0[j];
#pragma unroll
        for (int j = 0; j < 16; ++j) acc[j] += xv.y * w0[64 + j];
#pragma unroll
        for (int j = 0; j < 16; ++j) acc[j] += xv.z * w0[128 + j];
#pragma unroll
        for (int j = 0; j < 16; ++j) acc[j] += xv.w * w0[192 + j];
    }
    float* o = out + (size_t)row * DD + j0;
    if (RELU_ACC) {
#pragma unroll
        for (int j = 0; j < 4; ++j) {
            float4 cur = ((float4*)o)[j];
            cur.x += fmaxf(acc[4 * j + 0], 0.f);
            cur.y += fmaxf(acc[4 * j + 1], 0.f);
            cur.z += fmaxf(acc[4 * j + 2], 0.f);
            cur.w += fmaxf(acc[4 * j + 3], 0.f);
            ((float4*)o)[j] = cur;
        }
    } else {
#pragma unroll
        for (int j = 0; j < 4; ++j)
            ((float4*)o)[j] = make_float4(acc[4 * j], acc[4 * j + 1], acc[4 * j + 2], acc[4 * j + 3]);
    }
}

// gu[j] = 0.5*(gus_sel[j] + EMB[j]) for j<B; gi[j-B] = 0.5*(gis_sel[j-B] + EMB[j]) for j>=B
__global__ void k_blend(const float* __restrict__ gus_sel, const float* __restrict__ gis_sel,
                        const float* __restrict__ EMB, float* __restrict__ gu, float* __restrict__ gi,
                        int B) {
    int t = blockIdx.x * blockDim.x + threadIdx.x;
    if (t >= 2 * B * 16) return;
    int j = t >> 4, k = t & 15;
    float4 e = ((const float4*)(EMB + (size_t)j * DD))[k];
    if (j < B) {
        float4 s = ((const float4*)(gus_sel + (size_t)j * DD))[k];
        ((float4*)(gu + (size_t)j * DD))[k] =
            make_float4(0.5f * (s.x + e.x), 0.5f * (s.y + e.y), 0.5f * (s.z + e.z), 0.5f * (s.w + e.w));
    } else {
        int jj = j - B;
        float4 s = ((const float4*)(gis_sel + (size_t)jj * DD))[k];
        ((float4*)(gi + (size_t)jj * DD))[k] =
            make_float4(0.5f * (s.x + e.x), 0.5f * (s.y + e.y), 0.5f * (s.z + e.z), 0.5f * (s.w + e.w));
    }
}

// Q[r,d,e] = sum_s A[r,s]*P[s,d,e]
__global__ void k_build_Q(const float* __restrict__ A, const float* __restrict__ P,
                          float* __restrict__ Q, int R, int S) {
    int t = blockIdx.x * blockDim.x + threadIdx.x;
    if (t >= R * 4096) return;
    int r = t / 4096, de = t % 4096;
    float acc = 0.f;
    for (int s = 0; s < S; ++s) acc += A[r * S + s] * P[(size_t)s * 4096 + de];
    Q[t] = acc;
}

// pui[b,r]: one 64-lane wave per (b,r). Lane e: acc = gi[b,e] * sum_d gu[b,d]*Q[r,d,e]
__global__ __launch_bounds__(256) void k_pui2(const float* __restrict__ gu, const float* __restrict__ gi,
                                              const float* __restrict__ Q, float* __restrict__ pout,
                                              int B, int R) {
    int wid = (int)(((long long)blockIdx.x * blockDim.x + threadIdx.x) >> 6);
    int lane = threadIdx.x & 63;
    if (wid >= B * R) return;
    int b = wid / R, r = wid % R;
    const float* Qr = Q + (size_t)r * 4096;
    float gu_l = gu[(size_t)b * DD + lane];
    float gi_l = gi[(size_t)b * DD + lane];
    float acc = 0.f;
#pragma unroll 8
    for (int d = 0; d < 64; ++d) {
        float gud = __shfl(gu_l, d, 64);
        acc += gud * Qr[d * 64 + lane];
    }
    acc *= gi_l;
#pragma unroll
    for (int off = 32; off > 0; off >>= 1) acc += __shfl_down(acc, off, 64);
    if (lane == 0) pout[wid] = acc;
}

// xui[b] = sum_r rel[r]*softmax(pui[b,:])[r]
__global__ void k_softmax_out(const float* __restrict__ pui, const float* __restrict__ rel,
                              float* __restrict__ xui, int B, int R) {
    int b = blockIdx.x * blockDim.x + threadIdx.x;
    if (b >= B) return;
    float m = -1e30f;
    for (int r = 0; r < R; ++r) m = fmaxf(m, pui[(size_t)b * R + r]);
    float se = 0.f, sw = 0.f;
    for (int r = 0; r < R; ++r) {
        float e = expf(pui[(size_t)b * R + r] - m);
        se += e; sw += rel[r] * e;
    }
    xui[b] = sw / se;
}

extern "C" void kernel_launch(void* const* d_in, const int* in_sizes, int n_in,
                              void* d_out, int out_size, void* d_ws, size_t ws_size,
                              hipStream_t stream) {
    const float* Gu      = (const float*)d_in[0];
    const float* Gi      = (const float*)d_in[1];
    const float* Gus     = (const float*)d_in[2];
    const float* Gis     = (const float*)d_in[3];
    const float* W_conv  = (const float*)d_in[4];
    const float* W_dense = (const float*)d_in[5];
    const float* P       = (const float*)d_in[6];
    const float* A       = (const float*)d_in[7];
    const float* rel     = (const float*)d_in[8];
    const int*   ei_rel  = (const int*)d_in[9];
    const int*   ei_uu   = (const int*)d_in[10];
    const int*   ei_ii   = (const int*)d_in[11];
    const int*   user    = (const int*)d_in[12];
    const int*   item    = (const int*)d_in[13];

    const int U = in_sizes[0] / DD;
    const int I = in_sizes[1] / DD;
    const int N = U + I;
    const int R = in_sizes[8];
    const int S = in_sizes[6] / 4096;
    const int E_REL = in_sizes[9] / (2 * R);
    const int E_SIM = in_sizes[10] / 2;
    const int B = in_sizes[12];
    const size_t RN = (size_t)R * N;

    size_t edpElems = (size_t)U * C_SIM;
    if ((size_t)I * C_SIM > edpElems) edpElems = (size_t)I * C_SIM;
    if ((size_t)N * C_REL > edpElems) edpElems = (size_t)N * C_REL;
    edpElems = (edpElems + 3) & ~(size_t)3;

    int maxUI = U > I ? U : I;

    // ---- workspace layout (16B-aligned) ----
    char* p = (char*)d_ws;
    int*   edp     = (int*)p;   p += edpElems * 4;
    int*   cnt     = (int*)p;   p += RN * 4;
    float* dinv    = (float*)p; p += (size_t)(U + I) * 4;
    unsigned char* sel = (unsigned char*)p; p += ((size_t)N + 15) & ~(size_t)15;
    float* gus_sel = (float*)p; p += (size_t)B * DD * 4;
    float* gis_sel = (float*)p; p += (size_t)B * DD * 4;
    float* ACC     = (float*)p; p += (size_t)2 * B * DD * 4;
    float* TMP     = (float*)p; p += (size_t)2 * B * DD * 4;
    float* EMB     = (float*)p; p += (size_t)2 * B * DD * 4;
    float* gu      = (float*)p; p += (size_t)B * DD * 4;
    float* gi      = (float*)p; p += (size_t)B * DD * 4;
    float* Q       = (float*)p; p += (size_t)R * 4096 * 4;
    float* BIG0    = (float*)p; p += (size_t)maxUI * DD * 4;  // sim layer-1 out

    float* xui = (float*)d_out;
    float* pui = (float*)d_out + B;

    const int BT = 256;

    // ======== similarity graphs (padded CSR; full slot lists) ========
    hipMemsetAsync(cnt, 0, (size_t)(U + I) * 4, stream);
    // UU
    k_scatter_pad<<<cdiv(E_SIM, BT), BT, 0, stream>>>(ei_uu, ei_uu + E_SIM, E_SIM, cnt, edp, C_SIM);
    k_dinv_i<<<cdiv(U, BT), BT, 0, stream>>>(cnt, dinv, U);
    k_gather_pad<<<cdiv((long long)U * 16, BT), BT, 0, stream>>>(Gus, BIG0, edp, cnt, dinv, C_SIM, U);
    k_gather_sel_sim<<<cdiv((long long)B * 16, BT), BT, 0, stream>>>(BIG0, gus_sel, edp, cnt, dinv, C_SIM, user, B);
    // II (reuses edp after UU gathers, stream-serialized)
    k_scatter_pad<<<cdiv(E_SIM, BT), BT, 0, stream>>>(ei_ii, ei_ii + E_SIM, E_SIM, cnt + U, edp, C_SIM);
    k_dinv_i<<<cdiv(I, BT), BT, 0, stream>>>(cnt + U, dinv + U, I);
    k_gather_pad<<<cdiv((long long)I * 16, BT), BT, 0, stream>>>(Gis, BIG0, edp, cnt + U, dinv + U, C_SIM, I);
    k_gather_sel_sim<<<cdiv((long long)B * 16, BT), BT, 0, stream>>>(BIG0, gis_sel, edp, cnt + U, dinv + U, C_SIM, item, B);

    // ======== relational pass: filtered slots, selected destinations, W commuted ========
    hipMemsetAsync(cnt, 0, RN * 4, stream);
    hipMemsetAsync(sel, 0, (size_t)N, stream);
    hipMemsetAsync(ACC, 0, (size_t)2 * B * DD * 4, stream);
    k_mark<<<cdiv(2 * B, BT), BT, 0, stream>>>(sel, user, item, B, U);
    for (int r = 0; r < R; ++r) {
        const int* rrow = ei_rel + (size_t)r * 2 * E_REL;
        const int* rcol = rrow + E_REL;
        k_scatter_rel<<<cdiv(E_REL, BT), BT, 0, stream>>>(rrow, rcol, E_REL, cnt + (size_t)r * N, edp, C_REL, sel);
        k_gather_x0_rel<<<cdiv((long long)2 * B * 16, BT), BT, 0, stream>>>(Gu, Gi, U, TMP, edp,
                                                                            cnt + (size_t)r * N, C_REL,
                                                                            user, item, B);
        k_matmul64t<true><<<cdiv(2 * B, 64), BT, 0, stream>>>(TMP, W_conv + (size_t)r * 4096, ACC, 2 * B);
    }

    // ---- emb = ACC @ W_dense (2B rows); blend with sim results ----
    k_matmul64t<false><<<cdiv(2 * B, 64), BT, 0, stream>>>(ACC, W_dense, EMB, 2 * B);
    k_blend<<<cdiv((long long)2 * B * 16, BT), BT, 0, stream>>>(gus_sel, gis_sel, EMB, gu, gi, B);

    // ---- head ----
    k_build_Q<<<cdiv((long long)R * 4096, BT), BT, 0, stream>>>(A, P, Q, R, S);
    k_pui2<<<cdiv((long long)B * R * 64, BT), BT, 0, stream>>>(gu, gi, Q, pui, B, R);
    k_softmax_out<<<cdiv(B, BT), BT, 0, stream>>>(pui, rel, xui, B, R);
}